// Round 2
// baseline (1583.695 us; speedup 1.0000x reference)
//
#include <hip/hip_runtime.h>
#include <math.h>

// Problem constants
#define B_     4
#define L_     4096
#define D_     96
#define DIN_   192
#define NST_   16
#define RNK_   6
#define KC_    4
#define DEPTH_ 6
#define M_     (B_*L_)      // 16384 rows
#define NCH_   128          // scan chunks
#define CHL_   32           // chunk length  (NCH_*CHL_ == L_)
#define XDS_   48           // padded x_dbl row stride (dt_r @0..5, B @8..23, C @32..47)

__device__ __forceinline__ float siluf_(float x){ return x / (1.f + __expf(-x)); }

// ---------------------------------------------------------------------------
// Kernel 1: fused LayerNorm + in_proj GEMM.  M=16384, K=96, N=384.
// Block: 256 threads, 32 rows. micro-tile 8 rows x 6 cols per thread.
// ---------------------------------------------------------------------------
__global__ __launch_bounds__(256) void k_ln_inproj(
    const float* __restrict__ hin, const float* __restrict__ nw,
    const float* __restrict__ nb,  const float* __restrict__ w,
    float* __restrict__ xz)
{
  __shared__ float lds[32][100];   // padded: stride 100 mod 32 = 4 -> no 8-way conflicts
  const int t = threadIdx.x;
  const int rowblk = blockIdx.x * 32;

  // ---- LayerNorm phase: 8 threads per row, 12 elems each (two-pass) ----
  {
    const int r = t >> 3;
    const int e = (t & 7) * 12;
    const float* src = hin + (rowblk + r) * 96 + e;
    float v[12];
    #pragma unroll
    for (int i = 0; i < 3; i++){
      float4 f = ((const float4*)src)[i];
      v[i*4+0]=f.x; v[i*4+1]=f.y; v[i*4+2]=f.z; v[i*4+3]=f.w;
    }
    float s = 0.f;
    #pragma unroll
    for (int i = 0; i < 12; i++) s += v[i];
    s += __shfl_xor(s, 1); s += __shfl_xor(s, 2); s += __shfl_xor(s, 4);
    const float mu = s * (1.f/96.f);
    float q = 0.f;
    #pragma unroll
    for (int i = 0; i < 12; i++){ float dd = v[i]-mu; q += dd*dd; }
    q += __shfl_xor(q, 1); q += __shfl_xor(q, 2); q += __shfl_xor(q, 4);
    const float rstd = rsqrtf(q * (1.f/96.f) + 1e-5f);
    #pragma unroll
    for (int i = 0; i < 12; i++)
      lds[r][e+i] = (v[i]-mu)*rstd*nw[e+i] + nb[e+i];
  }
  __syncthreads();

  // ---- GEMM phase ----
  const int tx = t & 63;        // col lane
  const int ty = t >> 6;        // row group (4)
  float acc[8][6];
  #pragma unroll
  for (int i=0;i<8;i++)
    #pragma unroll
    for (int j=0;j<6;j++) acc[i][j]=0.f;

  for (int k4 = 0; k4 < 24; k4++){
    float4 a[8];
    #pragma unroll
    for (int i=0;i<8;i++) a[i] = *(const float4*)&lds[ty*8+i][k4*4];
    #pragma unroll
    for (int j=0;j<6;j++){
      const int c = tx + 64*j;
      const float4 wv = *(const float4*)&w[c*96 + k4*4];
      #pragma unroll
      for (int i=0;i<8;i++)
        acc[i][j] += a[i].x*wv.x + a[i].y*wv.y + a[i].z*wv.z + a[i].w*wv.w;
    }
  }
  #pragma unroll
  for (int i=0;i<8;i++){
    const int row = rowblk + ty*8 + i;
    #pragma unroll
    for (int j=0;j<6;j++)
      xz[row*384 + tx + 64*j] = acc[i][j];
  }
}

// ---------------------------------------------------------------------------
// Kernel 2 (fused): causal depthwise conv1d(K=4)+SiLU  +  x_proj (K=192,N=38)
//                   + dt_proj (K=6,N=192) + softplus.
// Block: 256 threads, 32 rows.
// ---------------------------------------------------------------------------
__global__ __launch_bounds__(256) void k_conv_xproj(
    const float* __restrict__ xz,  const float* __restrict__ cw,
    const float* __restrict__ cb,  const float* __restrict__ xpw,
    const float* __restrict__ dtw, const float* __restrict__ p_dtb,
    float* __restrict__ xs, float* __restrict__ xdbl, float* __restrict__ bdt)
{
  __shared__ float xc[35][192];
  __shared__ float a [32][192];
  __shared__ float xd[32][8];
  const int t = threadIdx.x;
  const int rowblk = blockIdx.x * 32;
  const bool batch_start = ((rowblk & (L_-1)) == 0);

  // ---- stage xc: global rows rowblk-3 .. rowblk+31, x-half of xz ----
  for (int i = t; i < 35*48; i += 256){
    const int rr = i / 48, c4 = i % 48;
    float4 v = make_float4(0.f,0.f,0.f,0.f);
    if (!(batch_start && rr < 3))
      v = *(const float4*)&xz[(rowblk - 3 + rr)*384 + c4*4];
    *(float4*)&xc[rr][c4*4] = v;
  }
  __syncthreads();

  // ---- conv1d + SiLU -> a (LDS) and xs (global) ----
  for (int i = t; i < 32*48; i += 256){
    const int r = i / 48, c4 = i % 48;
    const int d0 = c4*4;
    const float4 w0 = *(const float4*)&cw[(d0+0)*4];
    const float4 w1 = *(const float4*)&cw[(d0+1)*4];
    const float4 w2 = *(const float4*)&cw[(d0+2)*4];
    const float4 w3 = *(const float4*)&cw[(d0+3)*4];
    float4 acc = *(const float4*)&cb[d0];
    {
      float4 xv = *(const float4*)&xc[r+0][d0];
      acc.x += w0.x*xv.x; acc.y += w1.x*xv.y; acc.z += w2.x*xv.z; acc.w += w3.x*xv.w;
      xv = *(const float4*)&xc[r+1][d0];
      acc.x += w0.y*xv.x; acc.y += w1.y*xv.y; acc.z += w2.y*xv.z; acc.w += w3.y*xv.w;
      xv = *(const float4*)&xc[r+2][d0];
      acc.x += w0.z*xv.x; acc.y += w1.z*xv.y; acc.z += w2.z*xv.z; acc.w += w3.z*xv.w;
      xv = *(const float4*)&xc[r+3][d0];
      acc.x += w0.w*xv.x; acc.y += w1.w*xv.y; acc.z += w2.w*xv.z; acc.w += w3.w*xv.w;
    }
    float4 g;
    g.x = siluf_(acc.x); g.y = siluf_(acc.y);
    g.z = siluf_(acc.z); g.w = siluf_(acc.w);
    *(float4*)&a[r][d0] = g;
    *(float4*)&xs[(rowblk + r)*DIN_ + d0] = g;
  }
  __syncthreads();

  // ---- x_proj: x_dbl = a @ xpw^T (38 cols), padded layout ----
  for (int oi = t; oi < 32*38; oi += 256){
    const int r = oi / 38, c = oi % 38;
    const float* wr = xpw + c*192;
    float s = 0.f;
    #pragma unroll
    for (int k = 0; k < 192; k += 4){
      const float4 av = *(const float4*)&a[r][k];
      const float4 wv = *(const float4*)&wr[k];
      s += av.x*wv.x + av.y*wv.y + av.z*wv.z + av.w*wv.w;
    }
    const int pc = (c < 6) ? c : ((c < 22) ? c + 2 : c + 10);
    xdbl[(rowblk+r)*XDS_ + pc] = s;
    if (c < 6) xd[r][c] = s;
  }
  __syncthreads();

  // ---- dt = softplus(dt_r @ dtw^T + b) ----
  for (int oi = t; oi < 32*192; oi += 256){
    const int r = oi / 192, d = oi % 192;
    float s = p_dtb[d];
    #pragma unroll
    for (int j = 0; j < 6; j++) s += xd[r][j] * dtw[d*6+j];
    const float sp = (s > 20.f) ? s : log1pf(__expf(s));
    bdt[(rowblk+r)*DIN_ + d] = sp;
  }
}

// ---------------------------------------------------------------------------
// Kernel 3: scan pass A — per-chunk cumulative product P and suffix state S.
// Grid: B * NCH * 3 blocks of 64 threads; lane = channel d.
// ---------------------------------------------------------------------------
__global__ __launch_bounds__(64) void k_scan_a(
    const float* __restrict__ bdt, const float* __restrict__ xs,
    const float* __restrict__ xdbl, const float* __restrict__ Alog,
    float* __restrict__ Hc, float* __restrict__ Sc)
{
  const int bx = blockIdx.x;
  const int dg = bx % 3;
  const int ch = (bx/3) % NCH_;
  const int b  = bx / (3*NCH_);
  const int d  = dg*64 + threadIdx.x;

  float A[16];
  #pragma unroll
  for (int q = 0; q < 4; q++){
    const float4 al = *(const float4*)&Alog[d*16 + q*4];
    A[q*4+0] = -__expf(al.x); A[q*4+1] = -__expf(al.y);
    A[q*4+2] = -__expf(al.z); A[q*4+3] = -__expf(al.w);
  }
  float P[16], S[16];
  #pragma unroll
  for (int n=0;n<16;n++){ P[n]=1.f; S[n]=0.f; }

  const int row0 = b*L_ + ch*CHL_;
  const float* pdt = bdt  + row0*DIN_ + d;
  const float* pu  = xs   + row0*DIN_ + d;
  const float* pb  = xdbl + row0*XDS_ + 8;

  float dt_c = pdt[0];
  float u_c  = pu[0];
  float4 b4[4];
  #pragma unroll
  for (int q=0;q<4;q++) b4[q] = *(const float4*)&pb[q*4];

  for (int t0 = 0; t0 < CHL_; t0++){
    float dt_n = 0.f, u_n = 0.f;
    float4 n4[4] = {};
    if (t0+1 < CHL_){
      dt_n = pdt[(t0+1)*DIN_];
      u_n  = pu [(t0+1)*DIN_];
      #pragma unroll
      for (int q=0;q<4;q++) n4[q] = *(const float4*)&pb[(t0+1)*XDS_ + q*4];
    }
    const float du = dt_c * u_c;
    float Bv[16];
    #pragma unroll
    for (int q=0;q<4;q++){
      Bv[q*4+0]=b4[q].x; Bv[q*4+1]=b4[q].y; Bv[q*4+2]=b4[q].z; Bv[q*4+3]=b4[q].w;
    }
    #pragma unroll
    for (int n = 0; n < 16; n++){
      const float dA = __expf(dt_c * A[n]);
      P[n] *= dA;
      S[n] = S[n]*dA + du*Bv[n];
    }
    dt_c = dt_n; u_c = u_n;
    #pragma unroll
    for (int q=0;q<4;q++) b4[q] = n4[q];
  }
  const int o = ((b*NCH_ + ch)*DIN_ + d)*16;
  #pragma unroll
  for (int q = 0; q < 4; q++){
    *(float4*)&Hc[o + q*4] = make_float4(P[q*4+0],P[q*4+1],P[q*4+2],P[q*4+3]);
    *(float4*)&Sc[o + q*4] = make_float4(S[q*4+0],S[q*4+1],S[q*4+2],S[q*4+3]);
  }
}

// ---------------------------------------------------------------------------
// Kernel 4: scan pass B — sequential combine across chunks (tiny).
// One thread per (b,d,n) = 12288 threads.  Writes chunk-entry state IN PLACE
// over Sc (each element read before overwrite).
// ---------------------------------------------------------------------------
__global__ __launch_bounds__(256) void k_scan_b(
    const float* __restrict__ Hc, float* __restrict__ Sc)
{
  const int t = blockIdx.x*256 + threadIdx.x;
  const int b  = t / (DIN_*16);
  const int dn = t % (DIN_*16);
  float h = 0.f;
  for (int c = 0; c < NCH_; c++){
    const int o = (b*NCH_ + c)*DIN_*16 + dn;
    const float P = Hc[o];
    const float S = Sc[o];
    Sc[o] = h;               // entry state of chunk c
    h = P*h + S;
  }
}

// ---------------------------------------------------------------------------
// Kernel 5: scan pass C — recompute within chunk with known entry state,
// produce y.  hin == Sc (overwritten by pass B).
// ---------------------------------------------------------------------------
__global__ __launch_bounds__(64) void k_scan_c(
    const float* __restrict__ bdt, const float* __restrict__ xs,
    const float* __restrict__ xdbl, const float* __restrict__ Alog,
    const float* __restrict__ Dsk, const float* __restrict__ hin,
    float* __restrict__ y)
{
  const int bx = blockIdx.x;
  const int dg = bx % 3;
  const int ch = (bx/3) % NCH_;
  const int b  = bx / (3*NCH_);
  const int d  = dg*64 + threadIdx.x;

  float A[16];
  #pragma unroll
  for (int q = 0; q < 4; q++){
    const float4 al = *(const float4*)&Alog[d*16 + q*4];
    A[q*4+0] = -__expf(al.x); A[q*4+1] = -__expf(al.y);
    A[q*4+2] = -__expf(al.z); A[q*4+3] = -__expf(al.w);
  }
  float h[16];
  const int ho = ((b*NCH_ + ch)*DIN_ + d)*16;
  #pragma unroll
  for (int q = 0; q < 4; q++){
    const float4 hv = *(const float4*)&hin[ho + q*4];
    h[q*4+0]=hv.x; h[q*4+1]=hv.y; h[q*4+2]=hv.z; h[q*4+3]=hv.w;
  }
  const float dskip = Dsk[d];

  const int row0 = b*L_ + ch*CHL_;
  const float* pdt = bdt  + row0*DIN_ + d;
  const float* pu  = xs   + row0*DIN_ + d;
  const float* pb  = xdbl + row0*XDS_;

  float dt_c = pdt[0];
  float u_c  = pu[0];
  float4 b4[4], c4[4];
  #pragma unroll
  for (int q=0;q<4;q++){
    b4[q] = *(const float4*)&pb[8  + q*4];
    c4[q] = *(const float4*)&pb[32 + q*4];
  }

  for (int t0 = 0; t0 < CHL_; t0++){
    float dt_n = 0.f, u_n = 0.f;
    float4 nb4[4] = {}, nc4[4] = {};
    if (t0+1 < CHL_){
      dt_n = pdt[(t0+1)*DIN_];
      u_n  = pu [(t0+1)*DIN_];
      #pragma unroll
      for (int q=0;q<4;q++){
        nb4[q] = *(const float4*)&pb[(t0+1)*XDS_ + 8  + q*4];
        nc4[q] = *(const float4*)&pb[(t0+1)*XDS_ + 32 + q*4];
      }
    }
    const float du = dt_c * u_c;
    float Bv[16], Cv[16];
    #pragma unroll
    for (int q=0;q<4;q++){
      Bv[q*4+0]=b4[q].x; Bv[q*4+1]=b4[q].y; Bv[q*4+2]=b4[q].z; Bv[q*4+3]=b4[q].w;
      Cv[q*4+0]=c4[q].x; Cv[q*4+1]=c4[q].y; Cv[q*4+2]=c4[q].z; Cv[q*4+3]=c4[q].w;
    }
    float yv = 0.f;
    #pragma unroll
    for (int n = 0; n < 16; n++){
      const float dA = __expf(dt_c * A[n]);
      h[n] = h[n]*dA + du*Bv[n];
      yv += h[n]*Cv[n];
    }
    y[(row0 + t0)*DIN_ + d] = yv + dskip*u_c;
    dt_c = dt_n; u_c = u_n;
    #pragma unroll
    for (int q=0;q<4;q++){ b4[q] = nb4[q]; c4[q] = nc4[q]; }
  }
}

// ---------------------------------------------------------------------------
// Kernel 6: gating (y * silu(z)) fused into out_proj GEMM. K=192, N=96.
// Block: 256 threads, 32 rows; micro-tile 4 rows x 3 cols.
// ---------------------------------------------------------------------------
__global__ __launch_bounds__(256) void k_gate_outproj(
    const float* __restrict__ y, const float* __restrict__ xz,
    const float* __restrict__ ow, float* __restrict__ hout)
{
  __shared__ float a[32][192];
  const int t = threadIdx.x;
  const int rowblk = blockIdx.x * 32;

  for (int i = t; i < 32*48; i += 256){
    const int r = i / 48, c4 = i % 48;
    const float4 yv = *(const float4*)&y [(rowblk+r)*DIN_ + c4*4];
    const float4 zv = *(const float4*)&xz[(rowblk+r)*384 + 192 + c4*4];
    float4 g;
    g.x = yv.x * siluf_(zv.x); g.y = yv.y * siluf_(zv.y);
    g.z = yv.z * siluf_(zv.z); g.w = yv.w * siluf_(zv.w);
    *(float4*)&a[r][c4*4] = g;
  }
  __syncthreads();

  const int tx = t & 31;
  const int ty = t >> 5;
  float acc[4][3];
  #pragma unroll
  for (int i=0;i<4;i++)
    #pragma unroll
    for (int j=0;j<3;j++) acc[i][j]=0.f;

  for (int k4 = 0; k4 < 48; k4++){
    float4 av[4];
    #pragma unroll
    for (int i=0;i<4;i++) av[i] = *(const float4*)&a[ty*4+i][k4*4];
    #pragma unroll
    for (int j=0;j<3;j++){
      const int c = tx + 32*j;
      const float4 wv = *(const float4*)&ow[c*192 + k4*4];
      #pragma unroll
      for (int i=0;i<4;i++)
        acc[i][j] += av[i].x*wv.x + av[i].y*wv.y + av[i].z*wv.z + av[i].w*wv.w;
    }
  }
  #pragma unroll
  for (int i=0;i<4;i++){
    const int row = rowblk + ty*4 + i;
    #pragma unroll
    for (int j=0;j<3;j++)
      hout[row*96 + tx + 32*j] = acc[i][j];
  }
}

// ---------------------------------------------------------------------------
// Kernel 7: transpose conv2d weights to wt[tap][o][c] for f4 K-vectorization.
// ---------------------------------------------------------------------------
__global__ __launch_bounds__(256) void k_wtrans(
    const float* __restrict__ w, float* __restrict__ wt)
{
  const int idx = blockIdx.x*256 + threadIdx.x;
  if (idx < 96*96*9){
    const int tap = idx / 9216;
    const int rem = idx % 9216;
    const int o = rem / 96, c = rem % 96;
    wt[idx] = w[(o*96 + c)*9 + tap];
  }
}

// ---------------------------------------------------------------------------
// Kernel 8: 3x3 conv2d (9 shifted K=96 GEMMs from LDS halo tile) + bias
// + residual.  Block: (b, y, x-half): 32 pixels x 96 outputs.
// ---------------------------------------------------------------------------
__global__ __launch_bounds__(256) void k_conv2d(
    const float* __restrict__ h, const float* __restrict__ wt,
    const float* __restrict__ cb, const float* __restrict__ x0,
    float* __restrict__ out)
{
  __shared__ float lin[3][34][96];
  const int bx = blockIdx.x;
  const int xh = bx & 1;
  const int yy = (bx >> 1) & 63;
  const int b  = bx >> 7;
  const int x0p = xh * 32;
  const int t = threadIdx.x;

  // stage 3 rows x 34 px x 96 c halo tile (zero-padded)
  for (int i = t; i < 3*34*24; i += 256){
    const int c4 = i % 24;
    const int px = (i/24) % 34;
    const int dy = i / (24*34);
    const int gy = yy + dy - 1;
    const int gx = x0p + px - 1;
    float4 v = make_float4(0.f,0.f,0.f,0.f);
    if (gy >= 0 && gy < 64 && gx >= 0 && gx < 64)
      v = *(const float4*)&h[(b*4096 + gy*64 + gx)*96 + c4*4];
    *(float4*)&lin[dy][px][c4*4] = v;
  }
  __syncthreads();

  const int tc = t & 31;   // output-channel base
  const int tr = t >> 5;   // pixel group (8 groups x 4 px)
  float acc[4][3];
  #pragma unroll
  for (int i=0;i<4;i++)
    #pragma unroll
    for (int j=0;j<3;j++) acc[i][j]=0.f;

  for (int tap = 0; tap < 9; tap++){
    const int dy = tap / 3, dx = tap % 3;
    const float* wb = wt + tap*9216;
    for (int k4 = 0; k4 < 24; k4++){
      float4 av[4];
      #pragma unroll
      for (int i=0;i<4;i++)
        av[i] = *(const float4*)&lin[dy][tr*4+i+dx][k4*4];
      #pragma unroll
      for (int j=0;j<3;j++){
        const int o = tc + 32*j;
        const float4 wv = *(const float4*)&wb[o*96 + k4*4];
        #pragma unroll
        for (int i=0;i<4;i++)
          acc[i][j] += av[i].x*wv.x + av[i].y*wv.y + av[i].z*wv.z + av[i].w*wv.w;
      }
    }
  }
  #pragma unroll
  for (int i=0;i<4;i++){
    const int p = tr*4 + i;
    const int oidx0 = (b*4096 + yy*64 + x0p + p)*96;
    #pragma unroll
    for (int j=0;j<3;j++){
      const int o = tc + 32*j;
      out[oidx0 + o] = acc[i][j] + cb[o] + x0[oidx0 + o];
    }
  }
}

// ---------------------------------------------------------------------------
extern "C" void kernel_launch(void* const* d_in, const int* in_sizes, int n_in,
                              void* d_out, int out_size, void* d_ws, size_t ws_size,
                              hipStream_t stream)
{
  const float* x      = (const float*)d_in[0];
  const float* norm_w = (const float*)d_in[3];
  const float* norm_b = (const float*)d_in[4];
  const float* in_w   = (const float*)d_in[5];
  const float* cw     = (const float*)d_in[6];
  const float* cb     = (const float*)d_in[7];
  const float* xpw    = (const float*)d_in[8];
  const float* dtw    = (const float*)d_in[9];
  const float* dtbias = (const float*)d_in[10];
  const float* Alog   = (const float*)d_in[11];
  const float* Dsk    = (const float*)d_in[12];
  const float* ow     = (const float*)d_in[13];
  const float* c2w    = (const float*)d_in[14];
  const float* c2b    = (const float*)d_in[15];

  // workspace layout (floats); total ~21.4M floats = 85.4 MB
  float* ws   = (float*)d_ws;
  float* xz   = ws;                   // B*L*384        = 6,291,456
  float* xs   = xz   + 6291456;       // B*L*192        = 3,145,728
  float* xdbl = xs   + 3145728;       // M*48           =   786,432
  float* bdt  = xdbl + 786432;        // B*L*192        = 3,145,728
  float* yb   = bdt  + 3145728;       // B*L*192        = 3,145,728
  float* hb   = yb   + 3145728;       // B*L*96         = 1,572,864
  float* Hc   = hb   + 1572864;       // B*128*192*16   = 1,572,864
  float* Sc   = Hc   + 1572864;       // (also hin)     = 1,572,864
  float* wtb  = Sc   + 1572864;       // 9*96*96        =    82,944

  for (int i = 0; i < DEPTH_; i++){
    const float* hsrc = (i == 0) ? x : hb;
    k_ln_inproj  <<<512,  256, 0, stream>>>(hsrc, norm_w + i*96, norm_b + i*96,
                                            in_w + i*384*96, xz);
    k_conv_xproj <<<512,  256, 0, stream>>>(xz, cw + i*192*4, cb + i*192,
                                            xpw + i*38*192, dtw + i*192*6,
                                            dtbias + i*192, xs, xdbl, bdt);
    k_scan_a     <<<1536, 64,  0, stream>>>(bdt, xs, xdbl, Alog + i*192*16, Hc, Sc);
    k_scan_b     <<<48,   256, 0, stream>>>(Hc, Sc);
    k_scan_c     <<<1536, 64,  0, stream>>>(bdt, xs, xdbl, Alog + i*192*16,
                                            Dsk + i*192, Sc, yb);
    k_gate_outproj<<<512, 256, 0, stream>>>(yb, xz, ow + i*96*192, hb);
  }
  k_wtrans <<<324, 256, 0, stream>>>(c2w, wtb);
  k_conv2d <<<512, 256, 0, stream>>>(hb, wtb, c2b, x, (float*)d_out);
}